// Round 11
// baseline (455.915 us; speedup 1.0000x reference)
//
#include <hip/hip_runtime.h>
#include <hip/hip_bf16.h>
#include <stdint.h>

// CapsuleLayer dynamic routing — fp16 u_hat streaming, BW-tuned (R11).
// B=512, R=1152, C=10, O=16, I=8, 3 iters.
// R10 lessons: produce_u write-bound at 34% of achievable BW (12 waves/CU cap,
// 8B stores); consume under-occupied. This round:
//  - U layout [bt][r][lane][tt] (lane-pitch 80B): capsule pairs contiguous ->
//    16B stores/loads (5 per r instead of 10x8B).
//  - produce_u: 512-thr blocks, grid 768 -> 24 waves/CU (75%).
//  - consume_u: 256-thr blocks, grid 1536 (fits 4 blocks/CU at ~110 VGPR tier).
// ws: v f32 | s f32 | Wf bf16 | xT bf16 | bij f16 | U f16  (213.6 MB, proven fits)

#define BB 512
#define RR 1152
#define CCAP 10
#define II 8
#define CO 160
#define NBT 32

typedef __attribute__((ext_vector_type(8))) short bf16x8;
typedef __attribute__((ext_vector_type(4))) float f32x4;
typedef __attribute__((ext_vector_type(4))) _Float16 f16x4;
typedef __attribute__((ext_vector_type(8))) _Float16 f16x8;

__device__ inline short f2bf(float f) {
    uint32_t b = __float_as_uint(f);
    uint32_t r = (b + 0x7FFFu + ((b >> 16) & 1u)) >> 16;
    return (short)r;
}

// ---- prep: W -> bf16 (natural order == A-fragment order) ----
__global__ __launch_bounds__(256) void wconv(
    const float* __restrict__ W, unsigned short* __restrict__ Wf)
{
    const int i = (blockIdx.x * 256 + threadIdx.x) * 4;  // 1,474,560 total
    f32x4 w = *reinterpret_cast<const f32x4*>(W + i);
    ushort4 o;
    o.x = (unsigned short)f2bf(w[0]); o.y = (unsigned short)f2bf(w[1]);
    o.z = (unsigned short)f2bf(w[2]); o.w = (unsigned short)f2bf(w[3]);
    *reinterpret_cast<ushort4*>(Wf + i) = o;
}

// ---- prep: x[b][r][i] f32 -> xT[r][b][i] bf16 ----
__global__ __launch_bounds__(256) void xconv(
    const float* __restrict__ x, unsigned short* __restrict__ xT)
{
    const int tid = blockIdx.x * 256 + threadIdx.x;   // < 589,824
    const int r = tid >> 9, b = tid & 511;
    const float* xp = x + ((size_t)b * RR + r) * II;
    f32x4 lo = *reinterpret_cast<const f32x4*>(xp);
    f32x4 hi = *reinterpret_cast<const f32x4*>(xp + 4);
    ushort4 o0, o1;
    o0.x=(unsigned short)f2bf(lo[0]); o0.y=(unsigned short)f2bf(lo[1]);
    o0.z=(unsigned short)f2bf(lo[2]); o0.w=(unsigned short)f2bf(lo[3]);
    o1.x=(unsigned short)f2bf(hi[0]); o1.y=(unsigned short)f2bf(hi[1]);
    o1.z=(unsigned short)f2bf(hi[2]); o1.w=(unsigned short)f2bf(hi[3]);
    unsigned short* op = xT + ((size_t)r * BB + b) * II;
    *reinterpret_cast<ushort4*>(op)     = o0;
    *reinterpret_cast<ushort4*>(op + 4) = o1;
}

// ---- producer: U tiles (fp16, [bt][r][lane][tt]) + s0 = 0.1*sum_r u ----
// 512 threads (8 waves), grid 768 -> 24 waves/CU.
__global__ __launch_bounds__(512) void produce_u(
    const unsigned short* __restrict__ xT, const unsigned short* __restrict__ Wf,
    _Float16* __restrict__ U, float* __restrict__ s_out)
{
    __shared__ float spart[CO * 17];
    const int t  = threadIdx.x;
    const int bt = blockIdx.x & 31;
    const int sp = blockIdx.x >> 5;    // 0..23
    const int b0 = bt * 16;
    const int w  = t >> 6;             // 0..7
    const int l  = t & 63;
    const int lg = l >> 4;
    const int ln = l & 15;

    for (int i = t; i < CO * 17; i += 512) spart[i] = 0.0f;

    f32x4 sacc[CCAP];
    #pragma unroll
    for (int tt = 0; tt < CCAP; ++tt) {
        sacc[tt][0]=0.f; sacc[tt][1]=0.f; sacc[tt][2]=0.f; sacc[tt][3]=0.f;
    }

    const int rb = sp * 48 + w * 6;
    for (int rr = 0; rr < 6; ++rr) {
        const int r = rb + rr;
        bf16x8 bfr;
        #pragma unroll
        for (int j = 0; j < 8; ++j) bfr[j] = 0;
        if (l < 16)
            bfr = *reinterpret_cast<const bf16x8*>(xT + ((size_t)r * BB + b0 + l) * II);
        _Float16* Ub = U + (((size_t)bt * RR + r) * 64 + l) * 40;
        #pragma unroll
        for (int tp = 0; tp < 5; ++tp) {
            bf16x8 afr0 = *reinterpret_cast<const bf16x8*>(
                Wf + ((size_t)r * CCAP + 2*tp) * 128 + ln * 8);
            bf16x8 afr1 = *reinterpret_cast<const bf16x8*>(
                Wf + ((size_t)r * CCAP + 2*tp + 1) * 128 + ln * 8);
            f32x4 z; z[0]=0.f; z[1]=0.f; z[2]=0.f; z[3]=0.f;
            f32x4 uA = __builtin_amdgcn_mfma_f32_16x16x32_bf16(afr0, bfr, z, 0, 0, 0);
            f32x4 uB = __builtin_amdgcn_mfma_f32_16x16x32_bf16(afr1, bfr, z, 0, 0, 0);
            f16x8 h;
            h[0]=(_Float16)uA[0]; h[1]=(_Float16)uA[1];
            h[2]=(_Float16)uA[2]; h[3]=(_Float16)uA[3];
            h[4]=(_Float16)uB[0]; h[5]=(_Float16)uB[1];
            h[6]=(_Float16)uB[2]; h[7]=(_Float16)uB[3];
            *reinterpret_cast<f16x8*>(Ub + tp * 8) = h;
            sacc[2*tp][0]   += uA[0]; sacc[2*tp][1]   += uA[1];
            sacc[2*tp][2]   += uA[2]; sacc[2*tp][3]   += uA[3];
            sacc[2*tp+1][0] += uB[0]; sacc[2*tp+1][1] += uB[1];
            sacc[2*tp+1][2] += uB[2]; sacc[2*tp+1][3] += uB[3];
        }
    }
    __syncthreads();
    #pragma unroll
    for (int tt = 0; tt < CCAP; ++tt) {
        #pragma unroll
        for (int reg = 0; reg < 4; ++reg)
            atomicAdd(&spart[(tt * 16 + lg * 4 + reg) * 17 + ln], 0.1f * sacc[tt][reg]);
    }
    __syncthreads();
    #pragma unroll
    for (int q = 0; q < 5; ++q) {
        const int idx = q * 512 + t;          // < 2560
        const int co = idx % CO, b16 = idx / CO;
        atomicAdd(&s_out[(size_t)(b0 + b16) * CO + co], spart[co * 17 + b16]);
    }
}

// ---- consumer passes 1,2: stream U, routing math, no MFMA ----
// 256 threads (4 waves), grid 1536.
template <int K>
__global__ __launch_bounds__(256) void consume_u(
    const _Float16* __restrict__ U, const float* __restrict__ v_in,
    _Float16* __restrict__ bij, float* __restrict__ s_out)
{
    __shared__ float spart[CO * 17];
    const int t  = threadIdx.x;
    const int bt = blockIdx.x & 31;
    const int sp = blockIdx.x >> 5;    // 0..47
    const int b0 = bt * 16;
    const int w  = t >> 6;             // 0..3
    const int l  = t & 63;
    const int lg = l >> 4;
    const int ln = l & 15;

    for (int i = t; i < CO * 17; i += 256) spart[i] = 0.0f;

    f32x4 vf[CCAP];
    #pragma unroll
    for (int tt = 0; tt < CCAP; ++tt)
        vf[tt] = *reinterpret_cast<const f32x4*>(
            v_in + (size_t)(b0 + ln) * CO + tt * 16 + lg * 4);

    f32x4 sacc[CCAP];
    #pragma unroll
    for (int tt = 0; tt < CCAP; ++tt) {
        sacc[tt][0]=0.f; sacc[tt][1]=0.f; sacc[tt][2]=0.f; sacc[tt][3]=0.f;
    }

    const int rb = sp * 24 + w * 6;
    for (int rr = 0; rr < 6; ++rr) {
        const int r = rb + rr;
        const _Float16* Ub = U + (((size_t)bt * RR + r) * 64 + l) * 40;
        f16x8 uld[5];
        #pragma unroll
        for (int tp = 0; tp < 5; ++tp)
            uld[tp] = *reinterpret_cast<const f16x8*>(Ub + tp * 8);
        float a[CCAP];
        #pragma unroll
        for (int tt = 0; tt < CCAP; ++tt) {
            const int hb = (tt & 1) * 4;
            float p = (float)uld[tt>>1][hb+0]*vf[tt][0]
                    + (float)uld[tt>>1][hb+1]*vf[tt][1]
                    + (float)uld[tt>>1][hb+2]*vf[tt][2]
                    + (float)uld[tt>>1][hb+3]*vf[tt][3];
            p += __shfl_xor(p, 16);
            p += __shfl_xor(p, 32);
            a[tt] = p;
        }
        if (K == 2) {
            #pragma unroll
            for (int tt = 0; tt < CCAP; ++tt)
                a[tt] += (float)bij[((size_t)r * CCAP + tt) * BB + b0 + ln];
        } else {
            if (l < 16) {
                #pragma unroll
                for (int tt = 0; tt < CCAP; ++tt)
                    bij[((size_t)r * CCAP + tt) * BB + b0 + l] = (_Float16)a[tt];
            }
        }
        float m = a[0];
        #pragma unroll
        for (int tt = 1; tt < CCAP; ++tt) m = fmaxf(m, a[tt]);
        float ssum = 0.f;
        #pragma unroll
        for (int tt = 0; tt < CCAP; ++tt) { a[tt] = __expf(a[tt] - m); ssum += a[tt]; }
        float inv = 1.0f / ssum;
        #pragma unroll
        for (int tt = 0; tt < CCAP; ++tt) {
            const int hb = (tt & 1) * 4;
            float c = a[tt] * inv;
            sacc[tt][0] += c * (float)uld[tt>>1][hb+0];
            sacc[tt][1] += c * (float)uld[tt>>1][hb+1];
            sacc[tt][2] += c * (float)uld[tt>>1][hb+2];
            sacc[tt][3] += c * (float)uld[tt>>1][hb+3];
        }
    }
    __syncthreads();
    #pragma unroll
    for (int tt = 0; tt < CCAP; ++tt) {
        #pragma unroll
        for (int reg = 0; reg < 4; ++reg)
            atomicAdd(&spart[(tt * 16 + lg * 4 + reg) * 17 + ln], sacc[tt][reg]);
    }
    __syncthreads();
    #pragma unroll
    for (int q = 0; q < 10; ++q) {
        const int idx = q * 256 + t;          // < 2560
        const int co = idx % CO, b16 = idx / CO;
        atomicAdd(&s_out[(size_t)(b0 + b16) * CO + co], spart[co * 17 + b16]);
    }
}

// ---- bias + squash ----
__global__ __launch_bounds__(256) void squash_plain(
    const float* __restrict__ s, const float* __restrict__ bias,
    float* __restrict__ v_out)
{
    const int idx = blockIdx.x * 256 + threadIdx.x;   // < 81920
    const int co = idx % CO;
    float sv = s[idx] + bias[co];
    float n2 = sv * sv;
    n2 += __shfl_xor(n2, 1);
    n2 += __shfl_xor(n2, 2);
    n2 += __shfl_xor(n2, 4);
    n2 += __shfl_xor(n2, 8);
    float norm = sqrtf(n2);
    float scale = norm / (1.0f + n2 + 1e-8f);
    v_out[idx] = scale * sv;
}

extern "C" void kernel_launch(void* const* d_in, const int* in_sizes, int n_in,
                              void* d_out, int out_size, void* d_ws, size_t ws_size,
                              hipStream_t stream) {
    const float* x    = (const float*)d_in[0];
    const float* W    = (const float*)d_in[1];
    const float* bias = (const float*)d_in[2];
    float* out = (float*)d_out;
    char* ws = (char*)d_ws;

    float* v = (float*)(ws + 0);                         // 327,680 B
    float* s = (float*)(ws + 327680);                    // 327,680 B
    unsigned short* Wf = (unsigned short*)(ws + 655360); // 2,949,120 B
    unsigned short* xT = (unsigned short*)(ws + 3604480);// 9,437,184 B
    _Float16* bij = (_Float16*)(ws + 13041664);          // 11,796,480 B
    _Float16* U   = (_Float16*)(ws + 24838144);          // 188,743,680 B

    const dim3 blk(256);

    wconv<<<1440, blk, 0, stream>>>(W, Wf);
    xconv<<<2304, blk, 0, stream>>>(x, xT);

    hipMemsetAsync(s, 0, 81920 * sizeof(float), stream);
    produce_u<<<768, dim3(512), 0, stream>>>(xT, Wf, U, s);
    squash_plain<<<320, blk, 0, stream>>>(s, bias, v);

    hipMemsetAsync(s, 0, 81920 * sizeof(float), stream);
    consume_u<1><<<1536, blk, 0, stream>>>(U, v, bij, s);
    squash_plain<<<320, blk, 0, stream>>>(s, bias, v);

    hipMemsetAsync(s, 0, 81920 * sizeof(float), stream);
    consume_u<2><<<1536, blk, 0, stream>>>(U, v, bij, s);
    squash_plain<<<320, blk, 0, stream>>>(s, bias, out);
}

// Round 12
// 377.766 us; speedup vs baseline: 1.2069x; 1.2069x over previous
//
#include <hip/hip_runtime.h>
#include <hip/hip_bf16.h>
#include <stdint.h>

// CapsuleLayer dynamic routing — fp16 u_hat streaming (R12 = R10 + occupancy fix).
// B=512, R=1152, C=10, O=16, I=8, 3 iters.
// R11 lesson: 80B-stride lane layout broke store/load coalescing (2.38->1.44
// TB/s) and paired-MFMA packing bloated VGPR 36->120. REVERTED to R10's
// 8B-contiguous-per-lane U layout [bt][r][tt][lane] and single-MFMA loop.
// This round only raises occupancy: produce grid 768->1536 (3->6 blocks/CU at
// 36 VGPR), consume grid 768->1024 (exactly 4 blocks/CU at ~100 VGPR tier).
// ws: v f32 | s f32 | Wf bf16 | xT bf16 | bij f16 | U f16  (213.6 MB)

#define BB 512
#define RR 1152
#define CCAP 10
#define II 8
#define CO 160
#define NBT 32

typedef __attribute__((ext_vector_type(8))) short bf16x8;
typedef __attribute__((ext_vector_type(4))) float f32x4;
typedef __attribute__((ext_vector_type(4))) _Float16 f16x4;

__device__ inline short f2bf(float f) {
    uint32_t b = __float_as_uint(f);
    uint32_t r = (b + 0x7FFFu + ((b >> 16) & 1u)) >> 16;
    return (short)r;
}

// ---- prep: W -> bf16 (natural order == A-fragment order) ----
__global__ __launch_bounds__(256) void wconv(
    const float* __restrict__ W, unsigned short* __restrict__ Wf)
{
    const int i = (blockIdx.x * 256 + threadIdx.x) * 4;  // 1,474,560 total
    f32x4 w = *reinterpret_cast<const f32x4*>(W + i);
    ushort4 o;
    o.x = (unsigned short)f2bf(w[0]); o.y = (unsigned short)f2bf(w[1]);
    o.z = (unsigned short)f2bf(w[2]); o.w = (unsigned short)f2bf(w[3]);
    *reinterpret_cast<ushort4*>(Wf + i) = o;
}

// ---- prep: x[b][r][i] f32 -> xT[r][b][i] bf16 ----
__global__ __launch_bounds__(256) void xconv(
    const float* __restrict__ x, unsigned short* __restrict__ xT)
{
    const int tid = blockIdx.x * 256 + threadIdx.x;   // < 589,824
    const int r = tid >> 9, b = tid & 511;
    const float* xp = x + ((size_t)b * RR + r) * II;
    f32x4 lo = *reinterpret_cast<const f32x4*>(xp);
    f32x4 hi = *reinterpret_cast<const f32x4*>(xp + 4);
    ushort4 o0, o1;
    o0.x=(unsigned short)f2bf(lo[0]); o0.y=(unsigned short)f2bf(lo[1]);
    o0.z=(unsigned short)f2bf(lo[2]); o0.w=(unsigned short)f2bf(lo[3]);
    o1.x=(unsigned short)f2bf(hi[0]); o1.y=(unsigned short)f2bf(hi[1]);
    o1.z=(unsigned short)f2bf(hi[2]); o1.w=(unsigned short)f2bf(hi[3]);
    unsigned short* op = xT + ((size_t)r * BB + b) * II;
    *reinterpret_cast<ushort4*>(op)     = o0;
    *reinterpret_cast<ushort4*>(op + 4) = o1;
}

// ---- producer: U tiles (fp16, [bt][r][tt][lane]) + s0 = 0.1*sum_r u ----
// 256 thr, grid 1536 (NSPLIT_P=48) -> 6 blocks/CU at VGPR 36.
#define NSPLIT_P 48
__global__ __launch_bounds__(256) void produce_u(
    const unsigned short* __restrict__ xT, const unsigned short* __restrict__ Wf,
    _Float16* __restrict__ U, float* __restrict__ s_out)
{
    __shared__ float spart[CO * 17];
    const int t  = threadIdx.x;
    const int bt = blockIdx.x & 31;
    const int sp = blockIdx.x >> 5;    // 0..47
    const int b0 = bt * 16;
    const int l  = t & 63;
    const int lg = l >> 4;
    const int ln = l & 15;

    for (int i = t; i < CO * 17; i += 256) spart[i] = 0.0f;

    f32x4 sacc[CCAP];
    #pragma unroll
    for (int tt = 0; tt < CCAP; ++tt) {
        sacc[tt][0]=0.f; sacc[tt][1]=0.f; sacc[tt][2]=0.f; sacc[tt][3]=0.f;
    }

    const int rb = sp * 24 + (t >> 6) * 6;
    for (int rr = 0; rr < 6; ++rr) {
        const int r = rb + rr;
        bf16x8 bfr;
        #pragma unroll
        for (int j = 0; j < 8; ++j) bfr[j] = 0;
        if (l < 16)
            bfr = *reinterpret_cast<const bf16x8*>(xT + ((size_t)r * BB + b0 + l) * II);
        _Float16* Ub = U + ((size_t)bt * RR + r) * (CCAP * 256) + l * 4;
        #pragma unroll
        for (int tt = 0; tt < CCAP; ++tt) {
            bf16x8 afr = *reinterpret_cast<const bf16x8*>(
                Wf + ((size_t)r * CCAP + tt) * 128 + ln * 8);
            f32x4 z; z[0]=0.f; z[1]=0.f; z[2]=0.f; z[3]=0.f;
            f32x4 u = __builtin_amdgcn_mfma_f32_16x16x32_bf16(afr, bfr, z, 0, 0, 0);
            f16x4 h;
            h[0]=(_Float16)u[0]; h[1]=(_Float16)u[1];
            h[2]=(_Float16)u[2]; h[3]=(_Float16)u[3];
            *reinterpret_cast<f16x4*>(Ub + tt * 256) = h;
            sacc[tt][0] += u[0]; sacc[tt][1] += u[1];
            sacc[tt][2] += u[2]; sacc[tt][3] += u[3];
        }
    }
    __syncthreads();
    #pragma unroll
    for (int tt = 0; tt < CCAP; ++tt) {
        #pragma unroll
        for (int reg = 0; reg < 4; ++reg)
            atomicAdd(&spart[(tt * 16 + lg * 4 + reg) * 17 + ln], 0.1f * sacc[tt][reg]);
    }
    __syncthreads();
    #pragma unroll
    for (int q = 0; q < 10; ++q) {
        const int idx = q * 256 + t;          // < 2560
        const int co = idx % CO, b16 = idx / CO;
        atomicAdd(&s_out[(size_t)(b0 + b16) * CO + co], spart[co * 17 + b16]);
    }
}

// ---- consumer passes 1,2: stream U, routing math, no MFMA ----
// 256 thr, grid 1024 (NSPLIT_C=32) -> exactly 4 blocks/CU at ~100 VGPR tier.
#define NSPLIT_C 32
template <int K>
__global__ __launch_bounds__(256) void consume_u(
    const _Float16* __restrict__ U, const float* __restrict__ v_in,
    _Float16* __restrict__ bij, float* __restrict__ s_out)
{
    __shared__ float spart[CO * 17];
    const int t  = threadIdx.x;
    const int bt = blockIdx.x & 31;
    const int sp = blockIdx.x >> 5;    // 0..31
    const int b0 = bt * 16;
    const int l  = t & 63;
    const int lg = l >> 4;
    const int ln = l & 15;

    for (int i = t; i < CO * 17; i += 256) spart[i] = 0.0f;

    f32x4 vf[CCAP];
    #pragma unroll
    for (int tt = 0; tt < CCAP; ++tt)
        vf[tt] = *reinterpret_cast<const f32x4*>(
            v_in + (size_t)(b0 + ln) * CO + tt * 16 + lg * 4);

    f32x4 sacc[CCAP];
    #pragma unroll
    for (int tt = 0; tt < CCAP; ++tt) {
        sacc[tt][0]=0.f; sacc[tt][1]=0.f; sacc[tt][2]=0.f; sacc[tt][3]=0.f;
    }

    const int rb = sp * 36 + (t >> 6) * 9;
    for (int rr = 0; rr < 9; ++rr) {
        const int r = rb + rr;
        const _Float16* Ub = U + ((size_t)bt * RR + r) * (CCAP * 256) + l * 4;
        f16x4 uh[CCAP];                      // packed: 20 VGPRs
        #pragma unroll
        for (int tt = 0; tt < CCAP; ++tt)
            uh[tt] = *reinterpret_cast<const f16x4*>(Ub + tt * 256);
        float a[CCAP];
        #pragma unroll
        for (int tt = 0; tt < CCAP; ++tt) {
            float p = (float)uh[tt][0]*vf[tt][0] + (float)uh[tt][1]*vf[tt][1]
                    + (float)uh[tt][2]*vf[tt][2] + (float)uh[tt][3]*vf[tt][3];
            p += __shfl_xor(p, 16);
            p += __shfl_xor(p, 32);
            a[tt] = p;
        }
        if (K == 2) {
            #pragma unroll
            for (int tt = 0; tt < CCAP; ++tt)
                a[tt] += (float)bij[((size_t)r * CCAP + tt) * BB + b0 + ln];
        } else {
            if (l < 16) {
                #pragma unroll
                for (int tt = 0; tt < CCAP; ++tt)
                    bij[((size_t)r * CCAP + tt) * BB + b0 + l] = (_Float16)a[tt];
            }
        }
        float m = a[0];
        #pragma unroll
        for (int tt = 1; tt < CCAP; ++tt) m = fmaxf(m, a[tt]);
        float ssum = 0.f;
        #pragma unroll
        for (int tt = 0; tt < CCAP; ++tt) { a[tt] = __expf(a[tt] - m); ssum += a[tt]; }
        float inv = 1.0f / ssum;
        #pragma unroll
        for (int tt = 0; tt < CCAP; ++tt) {
            float c = a[tt] * inv;
            sacc[tt][0] += c * (float)uh[tt][0];
            sacc[tt][1] += c * (float)uh[tt][1];
            sacc[tt][2] += c * (float)uh[tt][2];
            sacc[tt][3] += c * (float)uh[tt][3];
        }
    }
    __syncthreads();
    #pragma unroll
    for (int tt = 0; tt < CCAP; ++tt) {
        #pragma unroll
        for (int reg = 0; reg < 4; ++reg)
            atomicAdd(&spart[(tt * 16 + lg * 4 + reg) * 17 + ln], sacc[tt][reg]);
    }
    __syncthreads();
    #pragma unroll
    for (int q = 0; q < 10; ++q) {
        const int idx = q * 256 + t;          // < 2560
        const int co = idx % CO, b16 = idx / CO;
        atomicAdd(&s_out[(size_t)(b0 + b16) * CO + co], spart[co * 17 + b16]);
    }
}

// ---- bias + squash ----
__global__ __launch_bounds__(256) void squash_plain(
    const float* __restrict__ s, const float* __restrict__ bias,
    float* __restrict__ v_out)
{
    const int idx = blockIdx.x * 256 + threadIdx.x;   // < 81920
    const int co = idx % CO;
    float sv = s[idx] + bias[co];
    float n2 = sv * sv;
    n2 += __shfl_xor(n2, 1);
    n2 += __shfl_xor(n2, 2);
    n2 += __shfl_xor(n2, 4);
    n2 += __shfl_xor(n2, 8);
    float norm = sqrtf(n2);
    float scale = norm / (1.0f + n2 + 1e-8f);
    v_out[idx] = scale * sv;
}

extern "C" void kernel_launch(void* const* d_in, const int* in_sizes, int n_in,
                              void* d_out, int out_size, void* d_ws, size_t ws_size,
                              hipStream_t stream) {
    const float* x    = (const float*)d_in[0];
    const float* W    = (const float*)d_in[1];
    const float* bias = (const float*)d_in[2];
    float* out = (float*)d_out;
    char* ws = (char*)d_ws;

    float* v = (float*)(ws + 0);                         // 327,680 B
    float* s = (float*)(ws + 327680);                    // 327,680 B
    unsigned short* Wf = (unsigned short*)(ws + 655360); // 2,949,120 B
    unsigned short* xT = (unsigned short*)(ws + 3604480);// 9,437,184 B
    _Float16* bij = (_Float16*)(ws + 13041664);          // 11,796,480 B
    _Float16* U   = (_Float16*)(ws + 24838144);          // 188,743,680 B

    const dim3 blk(256);

    wconv<<<1440, blk, 0, stream>>>(W, Wf);
    xconv<<<2304, blk, 0, stream>>>(x, xT);

    hipMemsetAsync(s, 0, 81920 * sizeof(float), stream);
    produce_u<<<NBT * NSPLIT_P, blk, 0, stream>>>(xT, Wf, U, s);
    squash_plain<<<320, blk, 0, stream>>>(s, bias, v);

    hipMemsetAsync(s, 0, 81920 * sizeof(float), stream);
    consume_u<1><<<NBT * NSPLIT_C, blk, 0, stream>>>(U, v, bij, s);
    squash_plain<<<320, blk, 0, stream>>>(s, bias, v);

    hipMemsetAsync(s, 0, 81920 * sizeof(float), stream);
    consume_u<2><<<NBT * NSPLIT_C, blk, 0, stream>>>(U, v, bij, s);
    squash_plain<<<320, blk, 0, stream>>>(s, bias, out);
}